// Round 1
// 2010.747 us; speedup vs baseline: 1.0216x; 1.0216x over previous
//
#include <hip/hip_runtime.h>
#include <hip/hip_bf16.h>

// AttenDecoder: B=64 T=32 S=64 E=128 H=256 V=32000.
// I/O is fp32 (per reference dtypes); compute uses bf16 MFMA with fp32 accum.
// Pipeline: gather/convert X -> MFMA GEMM gi -> per-batch GRU+attn recurrence
// (64 blocks x 1024 threads) -> MFMA GEMM relu-logits (fp32 out) -> log_softmax.

typedef __attribute__((ext_vector_type(8))) short  s8v;
typedef __attribute__((ext_vector_type(8))) __bf16 bf8v;
typedef __attribute__((ext_vector_type(4))) float  f4v;
typedef __attribute__((ext_vector_type(2))) float  f2v;

#define DEV static __device__ __forceinline__

DEV ushort f2b(float f) {            // round-to-nearest-even fp32 -> bf16
  unsigned u = __float_as_uint(f);
  u += 0x7fffu + ((u >> 16) & 1u);
  return (ushort)(u >> 16);
}
DEV float b2fs(short s) { return __uint_as_float(((unsigned)(ushort)s) << 16); }

// ---------------------------------------------------------------- gather X
// X[tb][640] = bf16([target[b,t,:], pos_feature[b,:], encoder_state[b,:], inp[b,t,:]])
__global__ __launch_bounds__(256) void k_gather(
    const float* __restrict__ target, const float* __restrict__ inp,
    const float* __restrict__ posf,   const float* __restrict__ encs,
    ushort* __restrict__ X) {
  int tb = blockIdx.x; int t = tb >> 6, b = tb & 63;
  size_t xrow = (size_t)tb * 640;
  for (int c = threadIdx.x; c < 640; c += 256) {
    float v;
    if (c < 128)      v = target[((size_t)b * 32 + t) * 128 + c];
    else if (c < 256) v = posf[(size_t)b * 128 + (c - 128)];
    else if (c < 512) v = encs[(size_t)b * 256 + (c - 256)];
    else              v = inp[((size_t)b * 32 + t) * 128 + (c - 512)];
    X[xrow + c] = f2b(v);
  }
}

// ------------------------------------------------- MFMA GEMM, B^T layout
// C[m,n] = sum_k A[m,k]*B[n,k] + bias[n].  A bf16 (ws), B fp32 (input weights,
// converted to bf16 in-register during staging).  128x128 tile, BK=32, 4 waves,
// each wave 64x64 via 4x4 of 16x16x32 bf16 MFMA.  LDS rows padded 32->40.
template <bool RELU>
__global__ __launch_bounds__(256) void k_gemm_bt(
    const ushort* __restrict__ A, const float* __restrict__ B,
    const float* __restrict__ bias, float* __restrict__ Out,
    int N, int K) {
  __shared__ __align__(16) ushort As[128 * 40];
  __shared__ __align__(16) ushort Bs[128 * 40];
  const int m0 = blockIdx.x * 128, n0 = blockIdx.y * 128;  // x=M: consecutive
  const int tid = threadIdx.x;                             // blocks share B-strip (L2)
  const int lane = tid & 63, wv = tid >> 6;
  const int wm = (wv >> 1) * 64, wn = (wv & 1) * 64;
  const int fr = lane & 15, fq = lane >> 4;
  const int srow = tid >> 2, scol = (tid & 3) * 8;
  f4v acc[4][4];
#pragma unroll
  for (int i = 0; i < 4; ++i)
#pragma unroll
    for (int j = 0; j < 4; ++j) acc[i][j] = {0.f, 0.f, 0.f, 0.f};
  const ushort* ag = A + (size_t)(m0 + srow) * K + scol;
  const float*  bg = B + (size_t)(n0 + srow) * K + scol;
  for (int k0 = 0; k0 < K; k0 += 32) {
    s8v a0 = *(const s8v*)(ag + k0);
    s8v a1 = *(const s8v*)(ag + k0 + (size_t)64 * K);
    f4v b00 = *(const f4v*)(bg + k0);
    f4v b01 = *(const f4v*)(bg + k0 + 4);
    f4v b10 = *(const f4v*)(bg + k0 + (size_t)64 * K);
    f4v b11 = *(const f4v*)(bg + k0 + (size_t)64 * K + 4);
    s8v b0, b1;
#pragma unroll
    for (int u = 0; u < 4; ++u) {
      b0[u]     = (short)f2b(b00[u]);
      b0[u + 4] = (short)f2b(b01[u]);
      b1[u]     = (short)f2b(b10[u]);
      b1[u + 4] = (short)f2b(b11[u]);
    }
    __syncthreads();
    *(s8v*)&As[srow * 40 + scol] = a0;
    *(s8v*)&As[(srow + 64) * 40 + scol] = a1;
    *(s8v*)&Bs[srow * 40 + scol] = b0;
    *(s8v*)&Bs[(srow + 64) * 40 + scol] = b1;
    __syncthreads();
    bf8v af[4], bfr[4];
#pragma unroll
    for (int i = 0; i < 4; ++i)
      af[i] = *(const bf8v*)&As[(wm + i * 16 + fr) * 40 + fq * 8];
#pragma unroll
    for (int j = 0; j < 4; ++j)
      bfr[j] = *(const bf8v*)&Bs[(wn + j * 16 + fr) * 40 + fq * 8];
#pragma unroll
    for (int i = 0; i < 4; ++i)
#pragma unroll
      for (int j = 0; j < 4; ++j)
        acc[i][j] = __builtin_amdgcn_mfma_f32_16x16x32_bf16(af[i], bfr[j],
                                                            acc[i][j], 0, 0, 0);
  }
  float bj[4];
#pragma unroll
  for (int j = 0; j < 4; ++j) bj[j] = bias[n0 + wn + j * 16 + fr];
#pragma unroll
  for (int i = 0; i < 4; ++i) {
#pragma unroll
    for (int j = 0; j < 4; ++j) {
#pragma unroll
      for (int r = 0; r < 4; ++r) {
        int gm = m0 + wm + i * 16 + fq * 4 + r;  // D row = quad*4+reg (m89)
        int gn = n0 + wn + j * 16 + fr;          // D col = lane&15
        float v = acc[i][j][r] + bj[j];
        if (RELU) v = fmaxf(v, 0.f);
        Out[(size_t)gm * N + gn] = v;
      }
    }
  }
}

// -------------------------------------------------------- recurrence
// One block per batch element b; all 32 timesteps inside the block.
// 1024 threads (16 waves -> 4 waves/SIMD for latency hiding).  Every dot
// product is lane-split with interleaved 4-float chunks (coalesced weight
// loads: the split lanes cover one 64B line) + shfl_xor butterfly reduce.
__global__ __launch_bounds__(1024) void k_recur(
    const float* __restrict__ gi_all,   // [32*64][768] (includes b_ih)
    const float* __restrict__ eo,       // [64][64][512] fp32
    const float* __restrict__ Whh,      // [768][256] fp32
    const float* __restrict__ bhh,      // [768]
    const float* __restrict__ Winw,     // [512][256] fp32
    const float* __restrict__ Winb,     // [512]
    ushort* __restrict__ feat,          // [32*64][768] bf16 out (GEMM A)
    float* __restrict__ hs_out) {       // [64][256] fp32 out (d_out base)
  const int b = blockIdx.x, tid = threadIdx.x;
  __shared__ __align__(16) float h[256];
  __shared__ __align__(16) float q[512];
  __shared__ float attnp[64];
  __shared__ float score[64];
  const float* eoB = eo + (size_t)b * 32768;

  // gh phase: hidden unit t = tid>>2, k-quarter lane p = tid&3 (interleaved)
  const int t = tid >> 2, p = tid & 3;
  const float* wr = Whh + (size_t)t * 256 + p * 4;
  const float* wz = wr + 65536;    // (t+256)*256
  const float* wn = wr + 131072;   // (t+512)*256
  const float bhr = bhh[t], bhz = bhh[t + 256], bhn = bhh[t + 512];

  // q phase: output qo = tid>>1, k-half lane qp = tid&1 (interleaved)
  const int qo = tid >> 1, qp = tid & 1;
  const float* wq = Winw + (size_t)qo * 256 + qp * 4;
  const float qb = Winb[qo];

  // attn phase: score row as = tid>>4, k-slice lane aj = tid&15 (interleaved)
  const int as = tid >> 4, aj = tid & 15;

  if (tid < 256) h[tid] = 0.f;
  __syncthreads();

  for (int st = 0; st < 32; ++st) {
    const float* gi = gi_all + ((size_t)st * 64 + b) * 768;
    float g0 = gi[t], g1 = gi[t + 256], g2 = gi[t + 512];  // hoist: hide latency
    // ---- gh = h @ Whh.T (rows t, t+256, t+512), 4-way k-split
    float ar = 0.f, az = 0.f, an = 0.f;
#pragma unroll
    for (int i = 0; i < 16; ++i) {
      f4v hv = *(const f4v*)&h[p * 4 + i * 16];
      f4v rv = *(const f4v*)(wr + i * 16);
      f4v zv = *(const f4v*)(wz + i * 16);
      f4v nv = *(const f4v*)(wn + i * 16);
#pragma unroll
      for (int u = 0; u < 4; ++u) {
        ar = fmaf(hv[u], rv[u], ar);
        az = fmaf(hv[u], zv[u], az);
        an = fmaf(hv[u], nv[u], an);
      }
    }
    ar += __shfl_xor(ar, 1); ar += __shfl_xor(ar, 2);
    az += __shfl_xor(az, 1); az += __shfl_xor(az, 2);
    an += __shfl_xor(an, 1); an += __shfl_xor(an, 2);
    float hnew = 0.f;
    if (p == 0) {
      float r = 1.f / (1.f + __expf(-(g0 + ar + bhr)));
      float z = 1.f / (1.f + __expf(-(g1 + az + bhz)));
      float e2 = __expf(2.f * (g2 + r * (an + bhn)));  // tanh, inf-safe
      float n = 1.f - 2.f / (e2 + 1.f);
      hnew = (1.f - z) * n + z * h[t];
    }
    __syncthreads();
    if (p == 0) h[t] = hnew;
    __syncthreads();
    // ---- q = h @ Winw.T + Winb, 2-way k-split, dual accumulators
    float a0 = 0.f, a1 = 0.f;
#pragma unroll
    for (int i = 0; i < 32; i += 2) {
      f4v h0 = *(const f4v*)&h[qp * 4 + i * 8];
      f4v w0 = *(const f4v*)(wq + i * 8);
      f4v h1 = *(const f4v*)&h[qp * 4 + i * 8 + 8];
      f4v w1 = *(const f4v*)(wq + i * 8 + 8);
#pragma unroll
      for (int u = 0; u < 4; ++u) {
        a0 = fmaf(h0[u], w0[u], a0);
        a1 = fmaf(h1[u], w1[u], a1);
      }
    }
    a0 += a1;
    a0 += __shfl_xor(a0, 1);
    if (qp == 0) q[qo] = a0 + qb;
    __syncthreads();
    // ---- attn[s] = eo[b,s,:] . q  — 16 lanes per s, interleaved chunks
    float aa = 0.f;
#pragma unroll
    for (int i = 0; i < 8; ++i) {
      int kk = aj * 4 + i * 64;
      f4v ev = *(const f4v*)(eoB + (size_t)as * 512 + kk);
      f4v qv = *(const f4v*)&q[kk];
#pragma unroll
      for (int u = 0; u < 4; ++u) aa = fmaf(ev[u], qv[u], aa);
    }
    aa += __shfl_xor(aa, 1); aa += __shfl_xor(aa, 2);
    aa += __shfl_xor(aa, 4); aa += __shfl_xor(aa, 8);
    if (aj == 0) attnp[as] = aa;
    __syncthreads();
    if (tid < 64) {  // softmax over S=64, all inside wave 0
      float a = attnp[tid];
      float m = a;
#pragma unroll
      for (int off = 32; off > 0; off >>= 1) m = fmaxf(m, __shfl_xor(m, off));
      float e = __expf(a - m);
      float ss = e;
#pragma unroll
      for (int off = 32; off > 0; off >>= 1) ss += __shfl_xor(ss, off);
      score[tid] = e / ss;
    }
    __syncthreads();
    // ---- h_star[d] = sum_s score[s]*eo[b,s,d]; feat = bf16([h_star, h])
    // d-pair = t (tid>>2), 4-way s-split lane p
    size_t row = ((size_t)st * 64 + b) * 768;
    {
      int d0 = 2 * t;
      float s0 = 0.f, s1 = 0.f;
#pragma unroll
      for (int i = 0; i < 16; ++i) {
        int s2 = p * 16 + i;
        float sc = score[s2];
        f2v ev = *(const f2v*)(eoB + (size_t)s2 * 512 + d0);
        s0 = fmaf(sc, ev.x, s0);
        s1 = fmaf(sc, ev.y, s1);
      }
      s0 += __shfl_xor(s0, 1); s0 += __shfl_xor(s0, 2);
      s1 += __shfl_xor(s1, 1); s1 += __shfl_xor(s1, 2);
      if (p == 0) {
        feat[row + d0] = f2b(s0);
        feat[row + d0 + 1] = f2b(s1);
      }
    }
    if (tid < 256) feat[row + 512 + tid] = f2b(h[tid]);
    // no trailing barrier: next write to LDS (h) is behind two barriers
  }
  if (tid < 256) hs_out[(size_t)b * 256 + tid] = h[tid];
}

// ----------------------------------------------- in-place log_softmax (fp32)
// One block per (t,b) row of 32000 relu'd logits in d_out.
__global__ __launch_bounds__(256) void k_logsm(float* __restrict__ out) {
  float* p = out + (size_t)blockIdx.x * 32000;
  const int t = threadIdx.x;
  __shared__ float red[4];
  float m = 0.f;  // relu'd values are >= 0
  for (int c = t; c < 4000; c += 256) {
    f4v a = *(const f4v*)(p + (size_t)c * 8);
    f4v b = *(const f4v*)(p + (size_t)c * 8 + 4);
    m = fmaxf(m, fmaxf(fmaxf(a.x, a.y), fmaxf(a.z, a.w)));
    m = fmaxf(m, fmaxf(fmaxf(b.x, b.y), fmaxf(b.z, b.w)));
  }
#pragma unroll
  for (int off = 32; off > 0; off >>= 1) m = fmaxf(m, __shfl_xor(m, off));
  if ((t & 63) == 0) red[t >> 6] = m;
  __syncthreads();
  m = fmaxf(fmaxf(red[0], red[1]), fmaxf(red[2], red[3]));
  float s = 0.f;
  for (int c = t; c < 4000; c += 256) {
    f4v a = *(const f4v*)(p + (size_t)c * 8);
    f4v b = *(const f4v*)(p + (size_t)c * 8 + 4);
    s += __expf(a.x - m) + __expf(a.y - m) + __expf(a.z - m) + __expf(a.w - m);
    s += __expf(b.x - m) + __expf(b.y - m) + __expf(b.z - m) + __expf(b.w - m);
  }
#pragma unroll
  for (int off = 32; off > 0; off >>= 1) s += __shfl_xor(s, off);
  __syncthreads();
  if ((t & 63) == 0) red[t >> 6] = s;
  __syncthreads();
  s = red[0] + red[1] + red[2] + red[3];
  const float L = m + logf(s);
  for (int c = t; c < 4000; c += 256) {
    f4v a = *(const f4v*)(p + (size_t)c * 8);
    f4v b = *(const f4v*)(p + (size_t)c * 8 + 4);
    a.x -= L; a.y -= L; a.z -= L; a.w -= L;
    b.x -= L; b.y -= L; b.z -= L; b.w -= L;
    *(f4v*)(p + (size_t)c * 8) = a;
    *(f4v*)(p + (size_t)c * 8 + 4) = b;
  }
}

extern "C" void kernel_launch(void* const* d_in, const int* in_sizes, int n_in,
                              void* d_out, int out_size, void* d_ws, size_t ws_size,
                              hipStream_t stream) {
  (void)in_sizes; (void)n_in; (void)out_size; (void)ws_size;
  const float* target = (const float*)d_in[0];
  const float* inp    = (const float*)d_in[1];
  const float* posf   = (const float*)d_in[2];
  const float* encs   = (const float*)d_in[3];
  const float* enco   = (const float*)d_in[4];
  const float* Wih    = (const float*)d_in[5];
  const float* Whh    = (const float*)d_in[6];
  const float* bih    = (const float*)d_in[7];
  const float* bhh    = (const float*)d_in[8];
  const float* Winw   = (const float*)d_in[9];
  const float* Winb   = (const float*)d_in[10];
  const float* Woutw  = (const float*)d_in[11];
  const float* Woutb  = (const float*)d_in[12];

  char* ws = (char*)d_ws;
  ushort* X    = (ushort*)(ws);              // 2048*640  bf16 = 2.62 MB
  float*  gi   = (float*)(ws + 0x300000);    // 2048*768  fp32 = 6.29 MB
  ushort* feat = (ushort*)(ws + 0x900000);   // 2048*768  bf16 = 3.15 MB
  float* hs    = (float*)d_out;              // [16384 hs][2048*32000 logits]
  float* logits = hs + 16384;

  k_gather<<<2048, 256, 0, stream>>>(target, inp, posf, encs, X);
  k_gemm_bt<false><<<dim3(16, 6), 256, 0, stream>>>(X, Wih, bih, gi, 768, 640);
  k_recur<<<64, 1024, 0, stream>>>(gi, enco, Whh, bhh, Winw, Winb, feat, hs);
  k_gemm_bt<true><<<dim3(16, 250), 256, 0, stream>>>(feat, Woutw, Woutb, logits,
                                                     32000, 768);
  k_logsm<<<2048, 256, 0, stream>>>(logits);
}

// Round 2
// 1894.579 us; speedup vs baseline: 1.0842x; 1.0613x over previous
//
#include <hip/hip_runtime.h>
#include <hip/hip_bf16.h>

// AttenDecoder: B=64 T=32 S=64 E=128 H=256 V=32000.
// I/O is fp32 (per reference dtypes); compute uses bf16 MFMA with fp32 accum.
// Pipeline: gather/convert X -> MFMA GEMM gi -> per-batch GRU+attn recurrence
// (64 blocks x 1024 threads, eo[b] staged in LDS) -> MFMA GEMM relu-logits ->
// in-place log_softmax.

typedef __attribute__((ext_vector_type(8))) short  s8v;
typedef __attribute__((ext_vector_type(8))) __bf16 bf8v;
typedef __attribute__((ext_vector_type(4))) float  f4v;
typedef __attribute__((ext_vector_type(2))) float  f2v;

#define DEV static __device__ __forceinline__

DEV ushort f2b(float f) {            // round-to-nearest-even fp32 -> bf16
  unsigned u = __float_as_uint(f);
  u += 0x7fffu + ((u >> 16) & 1u);
  return (ushort)(u >> 16);
}
DEV float b2fs(short s) { return __uint_as_float(((unsigned)(ushort)s) << 16); }

// ---------------------------------------------------------------- gather X
// X[tb][640] = bf16([target[b,t,:], pos_feature[b,:], encoder_state[b,:], inp[b,t,:]])
__global__ __launch_bounds__(256) void k_gather(
    const float* __restrict__ target, const float* __restrict__ inp,
    const float* __restrict__ posf,   const float* __restrict__ encs,
    ushort* __restrict__ X) {
  int tb = blockIdx.x; int t = tb >> 6, b = tb & 63;
  size_t xrow = (size_t)tb * 640;
  for (int c = threadIdx.x; c < 640; c += 256) {
    float v;
    if (c < 128)      v = target[((size_t)b * 32 + t) * 128 + c];
    else if (c < 256) v = posf[(size_t)b * 128 + (c - 128)];
    else if (c < 512) v = encs[(size_t)b * 256 + (c - 256)];
    else              v = inp[((size_t)b * 32 + t) * 128 + (c - 512)];
    X[xrow + c] = f2b(v);
  }
}

// ------------------------------------------------- MFMA GEMM, B^T layout
// C[m,n] = sum_k A[m,k]*B[n,k] + bias[n].  A bf16 (ws), B fp32 (input weights,
// converted to bf16 in-register during staging).  128x128 tile, BK=32, 4 waves,
// each wave 64x64 via 4x4 of 16x16x32 bf16 MFMA.  LDS rows padded 32->40.
template <bool RELU>
__global__ __launch_bounds__(256) void k_gemm_bt(
    const ushort* __restrict__ A, const float* __restrict__ B,
    const float* __restrict__ bias, float* __restrict__ Out,
    int N, int K) {
  __shared__ __align__(16) ushort As[128 * 40];
  __shared__ __align__(16) ushort Bs[128 * 40];
  const int m0 = blockIdx.x * 128, n0 = blockIdx.y * 128;  // x=M: consecutive
  const int tid = threadIdx.x;                             // blocks share B-strip (L2)
  const int lane = tid & 63, wv = tid >> 6;
  const int wm = (wv >> 1) * 64, wn = (wv & 1) * 64;
  const int fr = lane & 15, fq = lane >> 4;
  const int srow = tid >> 2, scol = (tid & 3) * 8;
  f4v acc[4][4];
#pragma unroll
  for (int i = 0; i < 4; ++i)
#pragma unroll
    for (int j = 0; j < 4; ++j) acc[i][j] = {0.f, 0.f, 0.f, 0.f};
  const ushort* ag = A + (size_t)(m0 + srow) * K + scol;
  const float*  bg = B + (size_t)(n0 + srow) * K + scol;
  for (int k0 = 0; k0 < K; k0 += 32) {
    s8v a0 = *(const s8v*)(ag + k0);
    s8v a1 = *(const s8v*)(ag + k0 + (size_t)64 * K);
    f4v b00 = *(const f4v*)(bg + k0);
    f4v b01 = *(const f4v*)(bg + k0 + 4);
    f4v b10 = *(const f4v*)(bg + k0 + (size_t)64 * K);
    f4v b11 = *(const f4v*)(bg + k0 + (size_t)64 * K + 4);
    s8v b0, b1;
#pragma unroll
    for (int u = 0; u < 4; ++u) {
      b0[u]     = (short)f2b(b00[u]);
      b0[u + 4] = (short)f2b(b01[u]);
      b1[u]     = (short)f2b(b10[u]);
      b1[u + 4] = (short)f2b(b11[u]);
    }
    __syncthreads();
    *(s8v*)&As[srow * 40 + scol] = a0;
    *(s8v*)&As[(srow + 64) * 40 + scol] = a1;
    *(s8v*)&Bs[srow * 40 + scol] = b0;
    *(s8v*)&Bs[(srow + 64) * 40 + scol] = b1;
    __syncthreads();
    bf8v af[4], bfr[4];
#pragma unroll
    for (int i = 0; i < 4; ++i)
      af[i] = *(const bf8v*)&As[(wm + i * 16 + fr) * 40 + fq * 8];
#pragma unroll
    for (int j = 0; j < 4; ++j)
      bfr[j] = *(const bf8v*)&Bs[(wn + j * 16 + fr) * 40 + fq * 8];
#pragma unroll
    for (int i = 0; i < 4; ++i)
#pragma unroll
      for (int j = 0; j < 4; ++j)
        acc[i][j] = __builtin_amdgcn_mfma_f32_16x16x32_bf16(af[i], bfr[j],
                                                            acc[i][j], 0, 0, 0);
  }
  float bj[4];
#pragma unroll
  for (int j = 0; j < 4; ++j) bj[j] = bias[n0 + wn + j * 16 + fr];
#pragma unroll
  for (int i = 0; i < 4; ++i) {
#pragma unroll
    for (int j = 0; j < 4; ++j) {
#pragma unroll
      for (int r = 0; r < 4; ++r) {
        int gm = m0 + wm + i * 16 + fq * 4 + r;  // D row = quad*4+reg (m89)
        int gn = n0 + wn + j * 16 + fr;          // D col = lane&15
        float v = acc[i][j][r] + bj[j];
        if (RELU) v = fmaxf(v, 0.f);
        Out[(size_t)gm * N + gn] = v;
      }
    }
  }
}

// -------------------------------------------------------- recurrence
// One block per batch element b; all 32 timesteps inside the block.
// 1024 threads (16 waves, 4/SIMD).  eo[b] (128KB fp32) is staged into LDS
// once, so the only per-step global traffic is the SHARED weight matrices
// (Whh, Winw) -> per-XCD L2 working set ~1.35MB -> resident (round-1 pathology
// was per-block private eo streams thrashing L2).  launch_bounds(1024,4)
// allows 128 VGPRs -> deeper load pipelining inside each barrier phase.
__global__ __launch_bounds__(1024, 4) void k_recur(
    const float* __restrict__ gi_all,   // [32*64][768] (includes b_ih)
    const float* __restrict__ eo,       // [64][64][512] fp32
    const float* __restrict__ Whh,      // [768][256] fp32
    const float* __restrict__ bhh,      // [768]
    const float* __restrict__ Winw,     // [512][256] fp32
    const float* __restrict__ Winb,     // [512]
    ushort* __restrict__ feat,          // [32*64][768] bf16 out (GEMM A)
    float* __restrict__ hs_out) {       // [64][256] fp32 out (d_out base)
  const int b = blockIdx.x, tid = threadIdx.x;
  __shared__ __align__(16) float eoS[64 * 512];   // 128 KB
  __shared__ __align__(16) float h[256];
  __shared__ __align__(16) float q[512];
  __shared__ float attnp[64];
  __shared__ float score[64];
  const float* eoB = eo + (size_t)b * 32768;
  // stage eo[b] -> LDS, coalesced f4v
#pragma unroll
  for (int i = 0; i < 8; ++i) {
    int idx = i * 1024 + tid;
    *(f4v*)&eoS[idx * 4] = *(const f4v*)(eoB + (size_t)idx * 4);
  }

  // gh phase: hidden unit t = tid>>2, k-quarter lane p = tid&3 (interleaved)
  const int t = tid >> 2, p = tid & 3;
  const float* wr = Whh + (size_t)t * 256 + p * 4;
  const float* wz = wr + 65536;    // (t+256)*256
  const float* wn = wr + 131072;   // (t+512)*256
  const float bhr = bhh[t], bhz = bhh[t + 256], bhn = bhh[t + 512];

  // q phase: output qo = tid>>1, k-half lane qp = tid&1 (interleaved)
  const int qo = tid >> 1, qp = tid & 1;
  const float* wq = Winw + (size_t)qo * 256 + qp * 4;
  const float qb = Winb[qo];

  // attn phase: score row as = tid>>4, k-slice lane aj = tid&15 (interleaved)
  const int as = tid >> 4, aj = tid & 15;

  if (tid < 256) h[tid] = 0.f;
  __syncthreads();

  for (int st = 0; st < 32; ++st) {
    const float* gi = gi_all + ((size_t)st * 64 + b) * 768;
    float g0 = gi[t], g1 = gi[t + 256], g2 = gi[t + 512];  // hoist: hide latency
    // ---- gh = h @ Whh.T (rows t, t+256, t+512), 4-way k-split
    float ar = 0.f, az = 0.f, an = 0.f;
#pragma unroll
    for (int i = 0; i < 16; ++i) {
      f4v hv = *(const f4v*)&h[p * 4 + i * 16];
      f4v rv = *(const f4v*)(wr + i * 16);
      f4v zv = *(const f4v*)(wz + i * 16);
      f4v nv = *(const f4v*)(wn + i * 16);
#pragma unroll
      for (int u = 0; u < 4; ++u) {
        ar = fmaf(hv[u], rv[u], ar);
        az = fmaf(hv[u], zv[u], az);
        an = fmaf(hv[u], nv[u], an);
      }
    }
    ar += __shfl_xor(ar, 1); ar += __shfl_xor(ar, 2);
    az += __shfl_xor(az, 1); az += __shfl_xor(az, 2);
    an += __shfl_xor(an, 1); an += __shfl_xor(an, 2);
    float hnew = 0.f;
    if (p == 0) {
      float r = 1.f / (1.f + __expf(-(g0 + ar + bhr)));
      float z = 1.f / (1.f + __expf(-(g1 + az + bhz)));
      float e2 = __expf(2.f * (g2 + r * (an + bhn)));  // tanh, inf-safe
      float n = 1.f - 2.f / (e2 + 1.f);
      hnew = (1.f - z) * n + z * h[t];
    }
    __syncthreads();
    if (p == 0) h[t] = hnew;
    __syncthreads();
    // ---- q = h @ Winw.T + Winb, 2-way k-split, dual accumulators
    float a0 = 0.f, a1 = 0.f;
#pragma unroll
    for (int i = 0; i < 32; i += 2) {
      f4v h0 = *(const f4v*)&h[qp * 4 + i * 8];
      f4v w0 = *(const f4v*)(wq + i * 8);
      f4v h1 = *(const f4v*)&h[qp * 4 + i * 8 + 8];
      f4v w1 = *(const f4v*)(wq + i * 8 + 8);
#pragma unroll
      for (int u = 0; u < 4; ++u) {
        a0 = fmaf(h0[u], w0[u], a0);
        a1 = fmaf(h1[u], w1[u], a1);
      }
    }
    a0 += a1;
    a0 += __shfl_xor(a0, 1);
    if (qp == 0) q[qo] = a0 + qb;
    __syncthreads();
    // ---- attn[s] = eoS[s,:] . q  — 16 lanes per s, interleaved LDS chunks
    float aa = 0.f;
#pragma unroll
    for (int i = 0; i < 8; ++i) {
      int kk = aj * 4 + i * 64;
      f4v ev = *(const f4v*)&eoS[as * 512 + kk];
      f4v qv = *(const f4v*)&q[kk];
#pragma unroll
      for (int u = 0; u < 4; ++u) aa = fmaf(ev[u], qv[u], aa);
    }
    aa += __shfl_xor(aa, 1); aa += __shfl_xor(aa, 2);
    aa += __shfl_xor(aa, 4); aa += __shfl_xor(aa, 8);
    if (aj == 0) attnp[as] = aa;
    __syncthreads();
    if (tid < 64) {  // softmax over S=64, all inside wave 0
      float a = attnp[tid];
      float m = a;
#pragma unroll
      for (int off = 32; off > 0; off >>= 1) m = fmaxf(m, __shfl_xor(m, off));
      float e = __expf(a - m);
      float ss = e;
#pragma unroll
      for (int off = 32; off > 0; off >>= 1) ss += __shfl_xor(ss, off);
      score[tid] = e / ss;
    }
    __syncthreads();
    // ---- h_star[d] = sum_s score[s]*eoS[s,d]; feat = bf16([h_star, h])
    // d-pair = t (tid>>2), 4-way s-split lane p
    size_t row = ((size_t)st * 64 + b) * 768;
    {
      int d0 = 2 * t;
      float s0 = 0.f, s1 = 0.f;
#pragma unroll
      for (int i = 0; i < 16; ++i) {
        int s2 = p * 16 + i;
        float sc = score[s2];
        f2v ev = *(const f2v*)&eoS[s2 * 512 + d0];
        s0 = fmaf(sc, ev.x, s0);
        s1 = fmaf(sc, ev.y, s1);
      }
      s0 += __shfl_xor(s0, 1); s0 += __shfl_xor(s0, 2);
      s1 += __shfl_xor(s1, 1); s1 += __shfl_xor(s1, 2);
      if (p == 0) {
        feat[row + d0] = f2b(s0);
        feat[row + d0 + 1] = f2b(s1);
      }
    }
    if (tid < 256) feat[row + 512 + tid] = f2b(h[tid]);
    // no trailing barrier: next write to LDS (h) is behind two barriers
  }
  if (tid < 256) hs_out[(size_t)b * 256 + tid] = h[tid];
}

// ----------------------------------------------- in-place log_softmax (fp32)
// One block per (t,b) row of 32000 relu'd logits in d_out.
__global__ __launch_bounds__(256) void k_logsm(float* __restrict__ out) {
  float* p = out + (size_t)blockIdx.x * 32000;
  const int t = threadIdx.x;
  __shared__ float red[4];
  float m = 0.f;  // relu'd values are >= 0
  for (int c = t; c < 4000; c += 256) {
    f4v a = *(const f4v*)(p + (size_t)c * 8);
    f4v b = *(const f4v*)(p + (size_t)c * 8 + 4);
    m = fmaxf(m, fmaxf(fmaxf(a.x, a.y), fmaxf(a.z, a.w)));
    m = fmaxf(m, fmaxf(fmaxf(b.x, b.y), fmaxf(b.z, b.w)));
  }
#pragma unroll
  for (int off = 32; off > 0; off >>= 1) m = fmaxf(m, __shfl_xor(m, off));
  if ((t & 63) == 0) red[t >> 6] = m;
  __syncthreads();
  m = fmaxf(fmaxf(red[0], red[1]), fmaxf(red[2], red[3]));
  float s = 0.f;
  for (int c = t; c < 4000; c += 256) {
    f4v a = *(const f4v*)(p + (size_t)c * 8);
    f4v b = *(const f4v*)(p + (size_t)c * 8 + 4);
    s += __expf(a.x - m) + __expf(a.y - m) + __expf(a.z - m) + __expf(a.w - m);
    s += __expf(b.x - m) + __expf(b.y - m) + __expf(b.z - m) + __expf(b.w - m);
  }
#pragma unroll
  for (int off = 32; off > 0; off >>= 1) s += __shfl_xor(s, off);
  __syncthreads();
  if ((t & 63) == 0) red[t >> 6] = s;
  __syncthreads();
  s = red[0] + red[1] + red[2] + red[3];
  const float L = m + logf(s);
  for (int c = t; c < 4000; c += 256) {
    f4v a = *(const f4v*)(p + (size_t)c * 8);
    f4v b = *(const f4v*)(p + (size_t)c * 8 + 4);
    a.x -= L; a.y -= L; a.z -= L; a.w -= L;
    b.x -= L; b.y -= L; b.z -= L; b.w -= L;
    *(f4v*)(p + (size_t)c * 8) = a;
    *(f4v*)(p + (size_t)c * 8 + 4) = b;
  }
}

extern "C" void kernel_launch(void* const* d_in, const int* in_sizes, int n_in,
                              void* d_out, int out_size, void* d_ws, size_t ws_size,
                              hipStream_t stream) {
  (void)in_sizes; (void)n_in; (void)out_size; (void)ws_size;
  const float* target = (const float*)d_in[0];
  const float* inp    = (const float*)d_in[1];
  const float* posf   = (const float*)d_in[2];
  const float* encs   = (const float*)d_in[3];
  const float* enco   = (const float*)d_in[4];
  const float* Wih    = (const float*)d_in[5];
  const float* Whh    = (const float*)d_in[6];
  const float* bih    = (const float*)d_in[7];
  const float* bhh    = (const float*)d_in[8];
  const float* Winw   = (const float*)d_in[9];
  const float* Winb   = (const float*)d_in[10];
  const float* Woutw  = (const float*)d_in[11];
  const float* Woutb  = (const float*)d_in[12];

  char* ws = (char*)d_ws;
  ushort* X    = (ushort*)(ws);              // 2048*640  bf16 = 2.62 MB
  float*  gi   = (float*)(ws + 0x300000);    // 2048*768  fp32 = 6.29 MB
  ushort* feat = (ushort*)(ws + 0x900000);   // 2048*768  bf16 = 3.15 MB
  float* hs    = (float*)d_out;              // [16384 hs][2048*32000 logits]
  float* logits = hs + 16384;

  k_gather<<<2048, 256, 0, stream>>>(target, inp, posf, encs, X);
  k_gemm_bt<false><<<dim3(16, 6), 256, 0, stream>>>(X, Wih, bih, gi, 768, 640);
  k_recur<<<64, 1024, 0, stream>>>(gi, enco, Whh, bhh, Winw, Winb, feat, hs);
  k_gemm_bt<true><<<dim3(16, 250), 256, 0, stream>>>(feat, Woutw, Woutb, logits,
                                                     32000, 768);
  k_logsm<<<2048, 256, 0, stream>>>(logits);
}